// Round 3
// baseline (127.752 us; speedup 1.0000x reference)
//
#include <hip/hip_runtime.h>

#define TLEN 2048
#define BROWS 2048
#define NSHIFT 31
#define MAXSH 15
#define BLOCK 256
#define EPSF 1e-8f

// padded LDS index for staged ext-targets: +2 dwords of pad per 8-float group
// (group stride 10 dwords -> 16 distinct even start-banks across a wave,
//  uniform 4 accesses/bank for b64 reads = near-minimal, alignment preserved)
__device__ __forceinline__ int padidx(int k) { return k + ((k >> 3) << 1); }

// smem layout (floats):
//   [0, 7936)     : phase A = padded ext targets (needs 2596) ; phase B = 31x256 transpose
//   [7936, 7952)  : rbuf (4 waves x 4 row-sums) -- survives both phases
//   [7952, 7956)  : wmax (per-wave max of raw dots)
__global__ void __launch_bounds__(BLOCK, 4)
pearson_fused_kernel(const float* __restrict__ preds,
                     const float* __restrict__ targets,
                     float* __restrict__ acc_slot,          // ws float[0], pre-zeroed
                     unsigned int* __restrict__ cnt_slot,   // ws u32[1],  pre-zeroed
                     float* __restrict__ out)
{
    __shared__ float smem[NSHIFT * BLOCK + 20];
    float* rbuf = smem + NSHIFT * BLOCK;
    float* wmax = rbuf + 16;

    const int tid  = threadIdx.x;
    const int wave = tid >> 6;
    const int lane = tid & 63;
    const int row  = blockIdx.x;
    const float* p_row = preds   + (size_t)row * TLEN;
    const float* t_row = targets + (size_t)row * TLEN;

    // ---- p: global -> registers directly (thread owns j in [8*tid, 8*tid+8)) ----
    float pc[8];
    {
        float4 a = ((const float4*)p_row)[2 * tid];
        float4 b = ((const float4*)p_row)[2 * tid + 1];
        pc[0] = a.x; pc[1] = a.y; pc[2] = a.z; pc[3] = a.w;
        pc[4] = b.x; pc[5] = b.y; pc[6] = b.z; pc[7] = b.w;
    }
    float sp = 0.f, spp = 0.f;
    #pragma unroll
    for (int i = 0; i < 8; ++i) { sp += pc[i]; spp = fmaf(pc[i], pc[i], spp); }

    // ---- t: coalesced load, row sums, stage ext into padded LDS ----
    float st = 0.f, stt = 0.f;
    #pragma unroll
    for (int r = 0; r < 2; ++r) {
        int f4 = tid + r * BLOCK;
        float4 tv = ((const float4*)t_row)[f4];
        st  += tv.x + tv.y + tv.z + tv.w;
        stt = fmaf(tv.x, tv.x, stt); stt = fmaf(tv.y, tv.y, stt);
        stt = fmaf(tv.z, tv.z, stt); stt = fmaf(tv.w, tv.w, stt);
        int k = f4 * 4 + MAXSH;          // ext index: ext[k] = t[(k-15) mod T]
        smem[padidx(k)]     = tv.x;
        smem[padidx(k + 1)] = tv.y;
        smem[padidx(k + 2)] = tv.z;
        smem[padidx(k + 3)] = tv.w;
    }
    if (tid < MAXSH) {
        smem[padidx(tid)] = t_row[TLEN - MAXSH + tid];
    } else if (tid >= 32 && tid < 32 + MAXSH) {
        int i = tid - 32;
        smem[padidx(TLEN + MAXSH + i)] = t_row[i];
    }

    // wave butterfly reduce of the 4 row sums (needed only by the final thread)
    #pragma unroll
    for (int off = 32; off > 0; off >>= 1) {
        sp  += __shfl_xor(sp,  off);
        spp += __shfl_xor(spp, off);
        st  += __shfl_xor(st,  off);
        stt += __shfl_xor(stt, off);
    }
    if (lane == 0) {
        rbuf[wave * 4 + 0] = sp;  rbuf[wave * 4 + 1] = spp;
        rbuf[wave * 4 + 2] = st;  rbuf[wave * 4 + 3] = stt;
    }
    __syncthreads();   // staging (and rbuf) visible

    // ---- sliding-window reads: padded offset of ext[8*tid + d] = 10*tid + d + 2*(d>>3) ----
    float w[38];
    {
        const int base = 10 * tid;
        #pragma unroll
        for (int q = 0; q < 19; ++q) {
            int d = 2 * q;               // even, never crosses a pad group (d%8 != 7)
            float2 v = *(const float2*)(smem + base + d + 2 * (d >> 3));
            w[d]     = v.x;
            w[d + 1] = v.y;
        }
    }
    __syncthreads();   // all window reads done before transpose clobbers smem

    // ---- 31 raw circular dots: acc[s] = sum_m pc[m] * ext[8*tid + m + s] ----
    float acc[NSHIFT];
    #pragma unroll
    for (int s = 0; s < NSHIFT; ++s) acc[s] = 0.f;
    #pragma unroll
    for (int m = 0; m < 8; ++m) {
        #pragma unroll
        for (int s = 0; s < NSHIFT; ++s) acc[s] = fmaf(pc[m], w[m + s], acc[s]);
    }

    // ---- reduce 31 partials across 256 threads: transpose + per-wave butterfly ----
    #pragma unroll
    for (int s = 0; s < NSHIFT; ++s) smem[s * BLOCK + tid] = acc[s];
    __syncthreads();

    float dmax = -1e30f;
    const int s0 = wave * 8;
    const int s1 = (s0 + 8 < NSHIFT) ? s0 + 8 : NSHIFT;
    for (int s = s0; s < s1; ++s) {
        float v = smem[s * BLOCK + lane]       + smem[s * BLOCK + lane + 64]
                + smem[s * BLOCK + lane + 128] + smem[s * BLOCK + lane + 192];
        #pragma unroll
        for (int off = 32; off > 0; off >>= 1) v += __shfl_xor(v, off);
        dmax = fmaxf(dmax, v);           // butterfly -> all lanes hold the total
    }
    if (lane == 0) wmax[wave] = dmax;
    __syncthreads();

    // ---- final: max over shifts commutes with the positive-scale affine map ----
    if (tid == 0) {
        float dot = fmaxf(fmaxf(wmax[0], wmax[1]), fmaxf(wmax[2], wmax[3]));
        float SP = 0, SPP = 0, ST = 0, STT = 0;
        #pragma unroll
        for (int w2 = 0; w2 < 4; ++w2) {
            SP += rbuf[w2 * 4 + 0]; SPP += rbuf[w2 * 4 + 1];
            ST += rbuf[w2 * 4 + 2]; STT += rbuf[w2 * 4 + 3];
        }
        const float invT = 1.0f / TLEN;
        float mp = SP * invT, mt = ST * invT;
        float varp = SPP - (float)TLEN * mp * mp;
        float vart = STT - (float)TLEN * mt * mt;
        float corr = (float)TLEN * mp * mt;
        float pear = (dot - corr) * rsqrtf((varp + EPSF) * (vart + EPSF));
        float contrib = (1.0f - fmaxf(pear, -1.0f)) * (1.0f / (float)BROWS);

        // last-block-done: release our contribution, count arrivals,
        // 2048th block acquires and publishes the total.
        atomicAdd(acc_slot, contrib);
        __threadfence();                               // release (device scope)
        unsigned int old = atomicAdd(cnt_slot, 1u);
        if (old == (unsigned int)(BROWS - 1)) {
            __threadfence();                           // acquire
            out[0] = __hip_atomic_load(acc_slot, __ATOMIC_RELAXED,
                                       __HIP_MEMORY_SCOPE_AGENT);
        }
    }
}

extern "C" void kernel_launch(void* const* d_in, const int* in_sizes, int n_in,
                              void* d_out, int out_size, void* d_ws, size_t ws_size,
                              hipStream_t stream) {
    const float* preds   = (const float*)d_in[0];
    const float* targets = (const float*)d_in[1];
    float*        acc = (float*)d_ws;            // ws[0]: float accumulator
    unsigned int* cnt = (unsigned int*)d_ws + 1; // ws[1]: arrival counter
    float* out = (float*)d_out;
    // poison-agnostic init of the two atomic slots (capturable, 8 bytes)
    hipMemsetAsync(d_ws, 0, 8, stream);
    pearson_fused_kernel<<<BROWS, BLOCK, 0, stream>>>(preds, targets, acc, cnt, out);
}

// Round 4
// 85.699 us; speedup vs baseline: 1.4907x; 1.4907x over previous
//
#include <hip/hip_runtime.h>

#define TLEN 2048
#define BROWS 2048
#define NSHIFT 31
#define MAXSH 15
#define BLOCK 256
#define EPSF 1e-8f

// padded LDS index for staged ext-targets: +2 dwords of pad per 8-float group
// (group stride 10 dwords; 8B alignment preserved for b64 reads)
__device__ __forceinline__ int padidx(int k) { return k + ((k >> 3) << 1); }

// smem layout (floats):
//   [0, 7936)     : phase A = padded ext targets (needs 2596) ; phase B = 31x256 transpose
//   [7936, 7952)  : rbuf (4 waves x 4 row-sums) -- survives both phases
//   [7952, 7956)  : wmax (per-wave max of raw dots)
__global__ void __launch_bounds__(BLOCK, 4)
pearson_rows_kernel(const float* __restrict__ preds,
                    const float* __restrict__ targets,
                    float* __restrict__ row_best)
{
    __shared__ float smem[NSHIFT * BLOCK + 20];
    float* rbuf = smem + NSHIFT * BLOCK;
    float* wmax = rbuf + 16;

    const int tid  = threadIdx.x;
    const int wave = tid >> 6;
    const int lane = tid & 63;
    const int row  = blockIdx.x;
    const float* p_row = preds   + (size_t)row * TLEN;
    const float* t_row = targets + (size_t)row * TLEN;

    // ---- p: global -> registers directly (thread owns j in [8*tid, 8*tid+8)) ----
    float pc[8];
    {
        float4 a = ((const float4*)p_row)[2 * tid];
        float4 b = ((const float4*)p_row)[2 * tid + 1];
        pc[0] = a.x; pc[1] = a.y; pc[2] = a.z; pc[3] = a.w;
        pc[4] = b.x; pc[5] = b.y; pc[6] = b.z; pc[7] = b.w;
    }
    float sp = 0.f, spp = 0.f;
    #pragma unroll
    for (int i = 0; i < 8; ++i) { sp += pc[i]; spp = fmaf(pc[i], pc[i], spp); }

    // ---- t: coalesced load, row sums, stage ext into padded LDS ----
    float st = 0.f, stt = 0.f;
    #pragma unroll
    for (int r = 0; r < 2; ++r) {
        int f4 = tid + r * BLOCK;
        float4 tv = ((const float4*)t_row)[f4];
        st  += tv.x + tv.y + tv.z + tv.w;
        stt = fmaf(tv.x, tv.x, stt); stt = fmaf(tv.y, tv.y, stt);
        stt = fmaf(tv.z, tv.z, stt); stt = fmaf(tv.w, tv.w, stt);
        int k = f4 * 4 + MAXSH;          // ext index: ext[k] = t[(k-15) mod T]
        smem[padidx(k)]     = tv.x;
        smem[padidx(k + 1)] = tv.y;
        smem[padidx(k + 2)] = tv.z;
        smem[padidx(k + 3)] = tv.w;
    }
    if (tid < MAXSH) {
        smem[padidx(tid)] = t_row[TLEN - MAXSH + tid];
    } else if (tid >= 32 && tid < 32 + MAXSH) {
        int i = tid - 32;
        smem[padidx(TLEN + MAXSH + i)] = t_row[i];
    }

    // wave butterfly reduce of the 4 row sums (needed only by the final thread)
    #pragma unroll
    for (int off = 32; off > 0; off >>= 1) {
        sp  += __shfl_xor(sp,  off);
        spp += __shfl_xor(spp, off);
        st  += __shfl_xor(st,  off);
        stt += __shfl_xor(stt, off);
    }
    if (lane == 0) {
        rbuf[wave * 4 + 0] = sp;  rbuf[wave * 4 + 1] = spp;
        rbuf[wave * 4 + 2] = st;  rbuf[wave * 4 + 3] = stt;
    }
    __syncthreads();   // staging (and rbuf) visible

    // ---- sliding-window reads, PINNED into VGPRs ----
    // padded offset of ext[8*tid + d] = 10*tid + d + 2*(d>>3).
    // The asm pins are compiler barriers: without them the compiler sinks these
    // ds_reads into the FMA loop (VGPR_Count 44 observed in R3 = ~248 scalar
    // ds_read_b32/thread instead of 19 ds_read_b64). Pinning forces the
    // register-resident form (~100 VGPR, still 4 waves/SIMD).
    float w[38];
    {
        const int base = 10 * tid;
        #pragma unroll
        for (int q = 0; q < 19; ++q) {
            int d = 2 * q;               // even, never crosses a pad group
            float2 v = *(const float2*)(smem + base + d + 2 * (d >> 3));
            w[d]     = v.x;
            w[d + 1] = v.y;
        }
        #pragma unroll
        for (int d = 0; d < 38; ++d) {
            asm volatile("" : "+v"(w[d]));   // force VGPR residency here
        }
    }
    __syncthreads();   // all window reads done before transpose clobbers smem

    // ---- 31 raw circular dots: acc[s] = sum_m pc[m] * ext[8*tid + m + s] ----
    float acc[NSHIFT];
    #pragma unroll
    for (int s = 0; s < NSHIFT; ++s) acc[s] = 0.f;
    #pragma unroll
    for (int m = 0; m < 8; ++m) {
        #pragma unroll
        for (int s = 0; s < NSHIFT; ++s) acc[s] = fmaf(pc[m], w[m + s], acc[s]);
    }

    // ---- reduce 31 partials across 256 threads: transpose + per-wave butterfly ----
    #pragma unroll
    for (int s = 0; s < NSHIFT; ++s) smem[s * BLOCK + tid] = acc[s];
    __syncthreads();

    float dmax = -1e30f;
    const int s0 = wave * 8;
    const int s1 = (s0 + 8 < NSHIFT) ? s0 + 8 : NSHIFT;
    for (int s = s0; s < s1; ++s) {
        float v = smem[s * BLOCK + lane]       + smem[s * BLOCK + lane + 64]
                + smem[s * BLOCK + lane + 128] + smem[s * BLOCK + lane + 192];
        #pragma unroll
        for (int off = 32; off > 0; off >>= 1) v += __shfl_xor(v, off);
        dmax = fmaxf(dmax, v);           // butterfly -> all lanes hold the total
    }
    if (lane == 0) wmax[wave] = dmax;
    __syncthreads();

    // ---- final: max over shifts commutes with the positive-scale affine map ----
    if (tid == 0) {
        float dot = fmaxf(fmaxf(wmax[0], wmax[1]), fmaxf(wmax[2], wmax[3]));
        float SP = 0, SPP = 0, ST = 0, STT = 0;
        #pragma unroll
        for (int w2 = 0; w2 < 4; ++w2) {
            SP += rbuf[w2 * 4 + 0]; SPP += rbuf[w2 * 4 + 1];
            ST += rbuf[w2 * 4 + 2]; STT += rbuf[w2 * 4 + 3];
        }
        const float invT = 1.0f / TLEN;
        float mp = SP * invT, mt = ST * invT;
        float varp = SPP - (float)TLEN * mp * mp;
        float vart = STT - (float)TLEN * mt * mt;
        float corr = (float)TLEN * mp * mt;
        float pear = (dot - corr) * rsqrtf((varp + EPSF) * (vart + EPSF));
        row_best[row] = fmaxf(pear, -1.0f);
    }
}

// 1 block: mean over 2048 per-row bests, write final loss
__global__ void __launch_bounds__(BLOCK)
pearson_finalize_kernel(const float* __restrict__ row_best, float* __restrict__ out)
{
    __shared__ float r[4];
    const int tid = threadIdx.x, wave = tid >> 6, lane = tid & 63;
    float4 a = ((const float4*)row_best)[tid];
    float4 b = ((const float4*)row_best)[tid + BLOCK];
    float s = (a.x + a.y) + (a.z + a.w) + (b.x + b.y) + (b.z + b.w);
    #pragma unroll
    for (int off = 32; off > 0; off >>= 1) s += __shfl_xor(s, off);
    if (lane == 0) r[wave] = s;
    __syncthreads();
    if (tid == 0)
        out[0] = 1.0f - (r[0] + r[1] + r[2] + r[3]) * (1.0f / (float)BROWS);
}

extern "C" void kernel_launch(void* const* d_in, const int* in_sizes, int n_in,
                              void* d_out, int out_size, void* d_ws, size_t ws_size,
                              hipStream_t stream) {
    const float* preds   = (const float*)d_in[0];
    const float* targets = (const float*)d_in[1];
    float* row_best = (float*)d_ws;          // 2048 floats of scratch
    float* out      = (float*)d_out;
    pearson_rows_kernel<<<BROWS, BLOCK, 0, stream>>>(preds, targets, row_best);
    pearson_finalize_kernel<<<1, BLOCK, 0, stream>>>(row_best, out);
}

// Round 5
// 80.900 us; speedup vs baseline: 1.5791x; 1.0593x over previous
//
#include <hip/hip_runtime.h>

#define TLEN 2048
#define BROWS 2048
#define NSHIFT 31
#define MAXSH 15
#define BLOCK 256
#define EPSF 1e-8f

// stride-12 padded LDS index: 8-float groups at 12-dword stride.
// 12*tid dwords = 48*tid bytes -> 16B-aligned b128 reads; lane starts
// 12l mod 32 cover all 32 banks once per 8 lanes -> conflict-free b128.
__device__ __forceinline__ int padidx12(int k) { return 12 * (k >> 3) + (k & 7); }

// ---- DPP wave64 reductions (VALU pipe, zero DS ops) ----
template<int CTRL, int RMASK, bool BC>
__device__ __forceinline__ float dpp_mov(float v, float old) {
    return __int_as_float(__builtin_amdgcn_update_dpp(
        __float_as_int(old), __float_as_int(v), CTRL, RMASK, 0xF, BC));
}
// sum across 64 lanes; result valid in lane 63
__device__ __forceinline__ float wave_sum_dpp(float v) {
    v += dpp_mov<0x111, 0xF, true>(v, 0.f);   // row_shr:1
    v += dpp_mov<0x112, 0xF, true>(v, 0.f);   // row_shr:2
    v += dpp_mov<0x114, 0xF, true>(v, 0.f);   // row_shr:4
    v += dpp_mov<0x118, 0xF, true>(v, 0.f);   // row_shr:8  -> lane15 of each row
    v += dpp_mov<0x142, 0xA, true>(v, 0.f);   // row_bcast15 -> rows 1,3
    v += dpp_mov<0x143, 0xC, true>(v, 0.f);   // row_bcast31 -> rows 2,3; lane63 = total
    return v;
}
// max across 64 lanes; result valid in lane 63 (old=v so masked lanes are no-ops)
__device__ __forceinline__ float wave_max_dpp(float v) {
    v = fmaxf(v, dpp_mov<0x111, 0xF, false>(v, v));
    v = fmaxf(v, dpp_mov<0x112, 0xF, false>(v, v));
    v = fmaxf(v, dpp_mov<0x114, 0xF, false>(v, v));
    v = fmaxf(v, dpp_mov<0x118, 0xF, false>(v, v));
    v = fmaxf(v, dpp_mov<0x142, 0xA, false>(v, v));
    v = fmaxf(v, dpp_mov<0x143, 0xC, false>(v, v));
    return v;
}

// smem layout (floats):
//   [0, 3120)      : stride-12 padded ext targets (260 groups)
//   [3120, 3376)   : wsum — 4 waves x 64 (only [0,31) columns written, stride 64
//                    keeps lane reads in-bounds)
//   [3376, 3392)   : rbuf — 4 waves x {sp,spp,st,stt}
__global__ void __launch_bounds__(BLOCK, 4)
pearson_rows_kernel(const float* __restrict__ preds,
                    const float* __restrict__ targets,
                    float* __restrict__ row_best)
{
    __shared__ float smem[3392];
    float* wsum = smem + 3120;
    float* rbuf = smem + 3376;

    const int tid  = threadIdx.x;
    const int wave = tid >> 6;
    const int lane = tid & 63;
    const int row  = blockIdx.x;
    const float* p_row = preds   + (size_t)row * TLEN;
    const float* t_row = targets + (size_t)row * TLEN;

    // ---- p: global -> registers (thread owns j in [8*tid, 8*tid+8)) ----
    float pc[8];
    {
        float4 a = ((const float4*)p_row)[2 * tid];
        float4 b = ((const float4*)p_row)[2 * tid + 1];
        pc[0] = a.x; pc[1] = a.y; pc[2] = a.z; pc[3] = a.w;
        pc[4] = b.x; pc[5] = b.y; pc[6] = b.z; pc[7] = b.w;
    }
    float sp = 0.f, spp = 0.f;
    #pragma unroll
    for (int i = 0; i < 8; ++i) { sp += pc[i]; spp = fmaf(pc[i], pc[i], spp); }

    // ---- t: coalesced load, row sums, stage ext into stride-12 LDS ----
    float st = 0.f, stt = 0.f;
    #pragma unroll
    for (int r = 0; r < 2; ++r) {
        int f4 = tid + r * BLOCK;
        float4 tv = ((const float4*)t_row)[f4];
        st  += tv.x + tv.y + tv.z + tv.w;
        stt = fmaf(tv.x, tv.x, stt); stt = fmaf(tv.y, tv.y, stt);
        stt = fmaf(tv.z, tv.z, stt); stt = fmaf(tv.w, tv.w, stt);
        int k = f4 * 4 + MAXSH;              // ext[k] = t[(k-15) mod T]
        smem[padidx12(k)]     = tv.x;
        smem[padidx12(k + 1)] = tv.y;
        smem[padidx12(k + 2)] = tv.z;
        smem[padidx12(k + 3)] = tv.w;
    }
    if (tid < MAXSH) {
        smem[padidx12(tid)] = t_row[TLEN - MAXSH + tid];
    } else if (tid >= 32 && tid < 32 + MAXSH) {
        int i = tid - 32;
        smem[padidx12(TLEN + MAXSH + i)] = t_row[i];
    }

    // ---- stats: DPP reduce (VALU), lane63 writes one float4 ----
    sp  = wave_sum_dpp(sp);
    spp = wave_sum_dpp(spp);
    st  = wave_sum_dpp(st);
    stt = wave_sum_dpp(stt);
    if (lane == 63) {
        *(float4*)(rbuf + wave * 4) = make_float4(sp, spp, st, stt);
    }
    __syncthreads();   // staging (and rbuf) visible

    // ---- window: 9x ds_read_b128 + 1x b64, conflict-free, pinned to VGPRs ----
    float w[38];
    {
        const float* g = smem + 12 * tid;
        #pragma unroll
        for (int q = 0; q < 4; ++q) {
            float4 a = *(const float4*)(g + 12 * q);
            float4 b = *(const float4*)(g + 12 * q + 4);
            w[8*q + 0] = a.x; w[8*q + 1] = a.y; w[8*q + 2] = a.z; w[8*q + 3] = a.w;
            w[8*q + 4] = b.x; w[8*q + 5] = b.y; w[8*q + 6] = b.z; w[8*q + 7] = b.w;
        }
        float4 c = *(const float4*)(g + 48);
        float2 e = *(const float2*)(g + 52);
        w[32] = c.x; w[33] = c.y; w[34] = c.z; w[35] = c.w;
        w[36] = e.x; w[37] = e.y;
        // compiler barrier: without it the loads legally sink into the FMA
        // loop (no clobber barrier anymore) -> 248 scalar ds_read_b32/thread
        #pragma unroll
        for (int d = 0; d < 38; ++d) asm volatile("" : "+v"(w[d]));
    }

    // ---- 31 raw circular dots: acc[s] = sum_m pc[m] * ext[8*tid + m + s] ----
    float acc[NSHIFT];
    #pragma unroll
    for (int s = 0; s < NSHIFT; ++s) acc[s] = 0.f;
    #pragma unroll
    for (int m = 0; m < 8; ++m) {
        #pragma unroll
        for (int s = 0; s < NSHIFT; ++s) acc[s] = fmaf(pc[m], w[m + s], acc[s]);
    }

    // ---- in-wave DPP reduce of all 31 shifts; lane63 holds the wave sums ----
    #pragma unroll
    for (int s = 0; s < NSHIFT; ++s) acc[s] = wave_sum_dpp(acc[s]);
    if (lane == 63) {
        float* dst = wsum + wave * 64;
        *(float4*)(dst +  0) = make_float4(acc[0],  acc[1],  acc[2],  acc[3]);
        *(float4*)(dst +  4) = make_float4(acc[4],  acc[5],  acc[6],  acc[7]);
        *(float4*)(dst +  8) = make_float4(acc[8],  acc[9],  acc[10], acc[11]);
        *(float4*)(dst + 12) = make_float4(acc[12], acc[13], acc[14], acc[15]);
        *(float4*)(dst + 16) = make_float4(acc[16], acc[17], acc[18], acc[19]);
        *(float4*)(dst + 20) = make_float4(acc[20], acc[21], acc[22], acc[23]);
        *(float4*)(dst + 24) = make_float4(acc[24], acc[25], acc[26], acc[27]);
        *(float2*)(dst + 28) = make_float2(acc[28], acc[29]);
        dst[30] = acc[30];
    }
    __syncthreads();

    // ---- final: wave 0 only. lane s (<31) owns shift s ----
    if (wave == 0) {
        float dot = wsum[lane] + wsum[64 + lane] + wsum[128 + lane] + wsum[192 + lane];
        float4 r0 = *(const float4*)(rbuf + 0);
        float4 r1 = *(const float4*)(rbuf + 4);
        float4 r2 = *(const float4*)(rbuf + 8);
        float4 r3 = *(const float4*)(rbuf + 12);
        float SP  = r0.x + r1.x + r2.x + r3.x;
        float SPP = r0.y + r1.y + r2.y + r3.y;
        float ST  = r0.z + r1.z + r2.z + r3.z;
        float STT = r0.w + r1.w + r2.w + r3.w;
        const float invT = 1.0f / TLEN;
        float mp = SP * invT, mt = ST * invT;
        float varp = SPP - (float)TLEN * mp * mp;
        float vart = STT - (float)TLEN * mt * mt;
        float corr = (float)TLEN * mp * mt;
        float pear = (dot - corr) * rsqrtf((varp + EPSF) * (vart + EPSF));
        float v = (lane < NSHIFT) ? pear : -3.0e38f;   // mask garbage lanes
        v = wave_max_dpp(v);
        if (lane == 63) row_best[row] = fmaxf(v, -1.0f);
    }
}

// 1 block: mean over 2048 per-row bests, write final loss
__global__ void __launch_bounds__(BLOCK)
pearson_finalize_kernel(const float* __restrict__ row_best, float* __restrict__ out)
{
    __shared__ float r[4];
    const int tid = threadIdx.x, wave = tid >> 6, lane = tid & 63;
    float4 a = ((const float4*)row_best)[tid];
    float4 b = ((const float4*)row_best)[tid + BLOCK];
    float s = (a.x + a.y) + (a.z + a.w) + (b.x + b.y) + (b.z + b.w);
    s = wave_sum_dpp(s);
    if (lane == 63) r[wave] = s;
    __syncthreads();
    if (tid == 0)
        out[0] = 1.0f - (r[0] + r[1] + r[2] + r[3]) * (1.0f / (float)BROWS);
}

extern "C" void kernel_launch(void* const* d_in, const int* in_sizes, int n_in,
                              void* d_out, int out_size, void* d_ws, size_t ws_size,
                              hipStream_t stream) {
    const float* preds   = (const float*)d_in[0];
    const float* targets = (const float*)d_in[1];
    float* row_best = (float*)d_ws;          // 2048 floats of scratch
    float* out      = (float*)d_out;
    pearson_rows_kernel<<<BROWS, BLOCK, 0, stream>>>(preds, targets, row_best);
    pearson_finalize_kernel<<<1, BLOCK, 0, stream>>>(row_best, out);
}